// Round 6
// baseline (2702.241 us; speedup 1.0000x reference)
//
#include <hip/hip_runtime.h>

// ---------------------------------------------------------------------------
// BiLSTM-CRF forward loss on MI355X (gfx950).
//
// Round-6 restructure: SINGLE WG PER GROUP, fp8 register-resident weights.
//   r5 (16 WG/group + atomic h exchange) hit its structural floor: 3 global
//   round-trips per step (store-ack, flag, uncached read) + MALL contention
//   = 4us/step. Eliminate them: in fp8 e4m3, each group's Whh+Wih fits the
//   register file of ONE CU (8 waves x 192 VGPR of weights). Recurrence
//   closes through LDS with 2 __syncthreads per step. Gates via
//   mfma_f32_16x16x32_fp8_fp8 (A/B use the same k->(lane,elem) map, so any
//   HW k-permutation cancels). c kept f32 in registers; h requantized fp8
//   per step; gates staged bf16; emissions fp8 (Wout in LDS).
//   x(t+1) gathered early + double-buffered (hides emb gather latency).
// Contract notes (rounds 0-3): output f32; mask int32.
// Workspace layout (bytes):
//   [0)         em: [2][128][512][20] f32            (10485760)
//   [10485760)  whh_f8: [2][64nt][8kt][64lane] i64   (524288)
//   [11010048)  wih_f8: [2][64nt][4kt][64lane] i64   (262144)
//   [11272192)  wout_f8: [2][2nt][8kt][64lane] i64   (16384)
//   [11288576)  bias: [2][1024] f32                  (8192)
//   [11296768)  partial: [128] f32
// ---------------------------------------------------------------------------

typedef float f32x4 __attribute__((ext_vector_type(4)));

#define MFMAF8(a, b, c) \
  __builtin_amdgcn_mfma_f32_16x16x32_fp8_fp8((a), (b), (c), 0, 0, 0)

__device__ __forceinline__ unsigned short f2bf(float x) {
  unsigned u = __float_as_uint(x);
  u += 0x7FFFu + ((u >> 16) & 1u);  // RNE
  return (unsigned short)(u >> 16);
}
__device__ __forceinline__ float bf2f(unsigned short h) {
  return __uint_as_float(((unsigned)h) << 16);
}
__device__ __forceinline__ float sigm(float x) {
  return __builtin_amdgcn_rcpf(1.f + __expf(-x));
}
__device__ __forceinline__ float tanh_(float x) {
  float e = __expf(2.f * x);
  return (e - 1.f) * __builtin_amdgcn_rcpf(e + 1.f);
}
__device__ __forceinline__ unsigned pack_fp8x4(float a, float b, float c, float d) {
  int p = __builtin_amdgcn_cvt_pk_fp8_f32(a, b, 0, false);
  p = __builtin_amdgcn_cvt_pk_fp8_f32(c, d, p, true);
  return (unsigned)p;
}

// ---------------------------------------------------------------------------
// K0: weight prep: f32 -> fp8 e4m3 MFMA B-fragments.
// Frag (ntile n, kt): lane l, byte e <- W[n*16+(l&15)][kt*32+(l>>4)*8+e]
// ---------------------------------------------------------------------------
__global__ __launch_bounds__(256) void prep_kernel(
    const float* __restrict__ Whh_f, const float* __restrict__ Whh_b,
    const float* __restrict__ Wih_f, const float* __restrict__ Wih_b,
    const float* __restrict__ Wout,
    const float* __restrict__ bih_f, const float* __restrict__ bhh_f,
    const float* __restrict__ bih_b, const float* __restrict__ bhh_b,
    long* __restrict__ whh, long* __restrict__ wih, long* __restrict__ wout,
    float* __restrict__ bias) {
  int bid = blockIdx.x, tid = threadIdx.x;
  if (bid < 256) {  // Whh: gid in [0, 65536)
    int gid = bid * 256 + tid;
    int l = gid & 63, kt = (gid >> 6) & 7, n = (gid >> 9) & 63, dir = gid >> 15;
    const float* src = dir ? Whh_b : Whh_f;
    int row = n * 16 + (l & 15), k0 = kt * 32 + ((l >> 4) << 3);
    float v[8];
#pragma unroll
    for (int e = 0; e < 8; ++e) v[e] = src[row * 256 + k0 + e];
    unsigned lo = pack_fp8x4(v[0], v[1], v[2], v[3]);
    unsigned hi = pack_fp8x4(v[4], v[5], v[6], v[7]);
    whh[gid] = (long)lo | ((long)hi << 32);
  } else if (bid < 384) {  // Wih: gid in [0, 32768)
    int gid = (bid - 256) * 256 + tid;
    int l = gid & 63, kt = (gid >> 6) & 3, n = (gid >> 8) & 63, dir = gid >> 14;
    const float* src = dir ? Wih_b : Wih_f;
    int row = n * 16 + (l & 15), k0 = kt * 32 + ((l >> 4) << 3);
    float v[8];
#pragma unroll
    for (int e = 0; e < 8; ++e) {
      int k = k0 + e;
      v[e] = (k < 100) ? src[row * 100 + k] : 0.f;
    }
    unsigned lo = pack_fp8x4(v[0], v[1], v[2], v[3]);
    unsigned hi = pack_fp8x4(v[4], v[5], v[6], v[7]);
    wih[gid] = (long)lo | ((long)hi << 32);
  } else if (bid < 392) {  // Wout: gid in [0, 2048)
    int gid = (bid - 384) * 256 + tid;
    if (gid < 2048) {
      int l = gid & 63, kt = (gid >> 6) & 7, n = (gid >> 9) & 1, dir = gid >> 10;
      int colt = n * 16 + (l & 15), k0 = kt * 32 + ((l >> 4) << 3);
      float v[8];
#pragma unroll
      for (int e = 0; e < 8; ++e)
        v[e] = (colt < 20) ? Wout[colt * 512 + dir * 256 + k0 + e] : 0.f;
      unsigned lo = pack_fp8x4(v[0], v[1], v[2], v[3]);
      unsigned hi = pack_fp8x4(v[4], v[5], v[6], v[7]);
      wout[gid] = (long)lo | ((long)hi << 32);
    }
  } else {  // bias: idx in [0, 2048)
    int idx = (bid - 392) * 256 + tid;
    if (idx < 2048) {
      int dir = idx >> 10, c = idx & 1023;
      bias[idx] = dir ? (bih_b[c] + bhh_b[c]) : (bih_f[c] + bhh_f[c]);
    }
  }
}

// ---------------------------------------------------------------------------
// K1: BiLSTM recurrence, one WG per (dir, batch-tile). grid=16, block=512.
// Wave w owns gate cols [w*128, (w+1)*128) = 8 ntiles of 16.
// ---------------------------------------------------------------------------
__global__ __launch_bounds__(512) void lstm_kernel(
    const int* __restrict__ sent, const float* __restrict__ emb,
    const long* __restrict__ whh, const long* __restrict__ wih,
    const long* __restrict__ wout, const float* __restrict__ bias,
    float* __restrict__ em_out)  // [2][128][512][20]
{
  __shared__ unsigned char h_lds[16][272];      // fp8 h(t-1), 256 data + pad
  __shared__ unsigned char x_lds[2][16][136];   // fp8 x, double-buffered
  __shared__ unsigned short g_T[1024][18];      // bf16 gates [col][row]
  __shared__ long wout_lds[2][8][64];           // fp8 Wout frags [nt][kt][lane]
  __shared__ float bias_lds[1024];

  const int tid = threadIdx.x;
  const int lid = tid & 63, w = tid >> 6;
  const int gid = blockIdx.x, dir = gid >> 3, bt = gid & 7, r0 = bt * 16;

  const int arow = lid & 15;       // A/C tile row-lane
  const int aq = lid >> 4;         // quarter
  const int rb = aq * 4;           // C-frag row base

  // ---- persistent fp8 weights in registers: 128+64 VGPRs ----
  long wh[8][8], wx[8][4];
  {
    const long* whh_d = whh + dir * 32768;
    const long* wih_d = wih + dir * 16384;
#pragma unroll
    for (int n = 0; n < 8; ++n) {
      int nt = w * 8 + n;
#pragma unroll
      for (int kt = 0; kt < 8; ++kt) wh[n][kt] = whh_d[(nt * 8 + kt) * 64 + lid];
#pragma unroll
      for (int kt = 0; kt < 4; ++kt) wx[n][kt] = wih_d[(nt * 4 + kt) * 64 + lid];
    }
  }
  // Wout + bias -> LDS
  {
    const long* wo_d = wout + dir * 1024;
    ((long*)wout_lds)[tid] = wo_d[tid];
    ((long*)wout_lds)[tid + 512] = wo_d[tid + 512];
    bias_lds[tid] = bias[dir * 1024 + tid];
    bias_lds[tid + 512] = bias[dir * 1024 + tid + 512];
  }
  // zero h, x (incl. padding)
  for (int i = tid; i < 16 * 272; i += 512) ((unsigned char*)h_lds)[i] = 0;
  for (int i = tid; i < 2 * 16 * 136; i += 512) ((unsigned char*)x_lds)[i] = 0;

  // h/c ownership: thread <-> (row ur, hidden cols ucg*8 .. +8)
  const int ur = tid & 15, ucg = tid >> 4;
  float creg[8];
#pragma unroll
  for (int j = 0; j < 8; ++j) creg[j] = 0.f;

  // x gather mapping: 400 chunks = (row 0..15) x (25 float4)
  const int rowA = tid / 25, cgA = tid - rowA * 25;
  const bool hasX = (tid < 400);

  // prologue: stage x(0)
  if (hasX) {
    int t0 = dir ? 511 : 0;
    int sid = sent[(r0 + rowA) * 512 + t0];
    float4 v = *(const float4*)&emb[sid * 100 + cgA * 4];
    *(unsigned*)&x_lds[0][rowA][cgA * 4] = pack_fp8x4(v.x, v.y, v.z, v.w);
  }
  __syncthreads();

  for (int t = 0; t < 512; ++t) {
    // issue x(t+1) gather early (latency hides under GEMM + update)
    float4 xN;
    const bool haveN = hasX && (t < 511);
    if (haveN) {
      int te = dir ? (511 - (t + 1)) : (t + 1);
      int sid = sent[(r0 + rowA) * 512 + te];
      xN = *(const float4*)&emb[sid * 100 + cgA * 4];
    }

    // ---- gate GEMM: 96 fp8 MFMA; B-frags in registers ----
    f32x4 acc[8];
#pragma unroll
    for (int n = 0; n < 8; ++n) {
      float bb = bias_lds[w * 128 + n * 16 + arow];
      f32x4 a = {bb, bb, bb, bb};
      acc[n] = a;
    }
    const unsigned char(*xb)[136] =
        (const unsigned char(*)[136])x_lds[t & 1];
#pragma unroll
    for (int kt = 0; kt < 8; ++kt) {
      long a8 = *(const long*)&h_lds[arow][kt * 32 + aq * 8];
#pragma unroll
      for (int n = 0; n < 8; ++n) acc[n] = MFMAF8(a8, wh[n][kt], acc[n]);
    }
#pragma unroll
    for (int kt = 0; kt < 4; ++kt) {
      long a8 = *(const long*)&xb[arow][kt * 32 + aq * 8];
#pragma unroll
      for (int n = 0; n < 8; ++n) acc[n] = MFMAF8(a8, wx[n][kt], acc[n]);
    }

    // ---- emissions for h(t-1): waves 0-1, h_lds still holds h(t-1) ----
    if (w < 2 && t > 0) {
      f32x4 e = {0.f, 0.f, 0.f, 0.f};
#pragma unroll
      for (int kt = 0; kt < 8; ++kt) {
        long a8 = *(const long*)&h_lds[arow][kt * 32 + aq * 8];
        e = MFMAF8(a8, wout_lds[w][kt][lid], e);
      }
      int col = w * 16 + arow;
      if (col < 20) {
        int tp = dir ? (512 - t) : (t - 1);
        int base = ((dir * 128 + r0 + rb) * 512 + tp) * 20 + col;
#pragma unroll
        for (int r = 0; r < 4; ++r) em_out[base + r * 10240] = e[r];
      }
    }

    // ---- stage gates bf16, [col][row] ----
#pragma unroll
    for (int n = 0; n < 8; ++n) {
      int colL = w * 128 + n * 16 + arow;
      *(unsigned*)&g_T[colL][rb] =
          (unsigned)f2bf(acc[n][0]) | ((unsigned)f2bf(acc[n][1]) << 16);
      *(unsigned*)&g_T[colL][rb + 2] =
          (unsigned)f2bf(acc[n][2]) | ((unsigned)f2bf(acc[n][3]) << 16);
    }
    __syncthreads();  // B2: gates ready; all h_lds/x reads done

    // ---- h/c update: 8 hidden cols per thread ----
    {
      float hv[8];
#pragma unroll
      for (int j = 0; j < 8; ++j) {
        int c = ucg * 8 + j;
        float xi = bf2f(g_T[c][ur]);
        float xf = bf2f(g_T[256 + c][ur]);
        float xg = bf2f(g_T[512 + c][ur]);
        float xo = bf2f(g_T[768 + c][ur]);
        float cc = sigm(xf) * creg[j] + sigm(xi) * tanh_(xg);
        creg[j] = cc;
        hv[j] = sigm(xo) * tanh_(cc);
      }
      unsigned lo = pack_fp8x4(hv[0], hv[1], hv[2], hv[3]);
      unsigned hi = pack_fp8x4(hv[4], hv[5], hv[6], hv[7]);
      *(long*)&h_lds[ur][ucg * 8] = (long)lo | ((long)hi << 32);
    }
    // ---- x(t+1) -> LDS (other buffer) ----
    if (haveN) {
      *(unsigned*)&x_lds[(t + 1) & 1][rowA][cgA * 4] =
          pack_fp8x4(xN.x, xN.y, xN.z, xN.w);
    }
    __syncthreads();  // B3: h(t) + x(t+1) staged
  }

  // final emissions for h(511)
  if (w < 2) {
    f32x4 e = {0.f, 0.f, 0.f, 0.f};
#pragma unroll
    for (int kt = 0; kt < 8; ++kt) {
      long a8 = *(const long*)&h_lds[arow][kt * 32 + aq * 8];
      e = MFMAF8(a8, wout_lds[w][kt][lid], e);
    }
    int col = w * 16 + arow;
    if (col < 20) {
      int tp = dir ? 0 : 511;
      int base = ((dir * 128 + r0 + rb) * 512 + tp) * 20 + col;
#pragma unroll
      for (int r = 0; r < 4; ++r) em_out[base + r * 10240] = e[r];
    }
  }
}

// ---------------------------------------------------------------------------
// K2: CRF gold score + forward algorithm. 128 blocks x 64 threads.
// ---------------------------------------------------------------------------
__global__ __launch_bounds__(64) void crf_kernel(
    const float* __restrict__ emf, const float* __restrict__ embk,
    const int* __restrict__ tags, const int* __restrict__ maski,
    const float* __restrict__ bout, const float* __restrict__ trans,
    const float* __restrict__ start_t, const float* __restrict__ end_t,
    float* __restrict__ partial) {
  __shared__ float tr[400];
  const int b = blockIdx.x, tid = threadIdx.x;
  for (int i = tid; i < 400; i += 64) tr[i] = trans[i];
  __syncthreads();

  const int tp = tid;
  const bool act = tp < 20;
  float eT[20];
  if (act) {
#pragma unroll
    for (int t2 = 0; t2 < 20; ++t2) eT[t2] = __expf(tr[t2 * 20 + tp]);
  }
  const float* ef = emf + (size_t)b * 10240;
  const float* eb = embk + (size_t)b * 10240;
  const float bo = act ? bout[tp] : 0.f;

  float a = act ? (start_t[tp] + ef[tp] + eb[tp] + bo) : -1e30f;

  float efn = 0.f, ebn = 0.f;
  if (act) { efn = ef[20 + tp]; ebn = eb[20 + tp]; }

  for (int l = 1; l < 512; ++l) {
    float e_cur = efn + ebn + bo;
    if (act && l + 1 < 512) { efn = ef[(l + 1) * 20 + tp]; ebn = eb[(l + 1) * 20 + tp]; }
    float m = a;
#pragma unroll
    for (int o = 16; o > 0; o >>= 1) m = fmaxf(m, __shfl_xor(m, o, 32));
    float p = __expf(a - m);
    float s = 0.f;
#pragma unroll
    for (int t2 = 0; t2 < 20; ++t2) s += __shfl(p, t2, 32) * eT[t2];
    float anew = m + __logf(s) + e_cur;
    int mk = maski[b * 512 + l];
    if (act && mk) a = anew;
  }
  float v = act ? (a + end_t[tp]) : -1e30f;
  float m2 = v;
#pragma unroll
  for (int o = 16; o > 0; o >>= 1) m2 = fmaxf(m2, __shfl_xor(m2, o, 32));
  float s2 = __expf(v - m2);
#pragma unroll
  for (int o = 16; o > 0; o >>= 1) s2 += __shfl_xor(s2, o, 32);
  float logZ = m2 + __logf(s2);

  const int* tg = tags + b * 512;
  float sc = 0.f;
  int cnt = 0;
  for (int l = tid; l < 512; l += 64) {
    int mk = maski[b * 512 + l];
    cnt += mk ? 1 : 0;
    if (l >= 1 && mk) {
      int cur = tg[l], prev = tg[l - 1];
      sc += tr[prev * 20 + cur] + ef[l * 20 + cur] + eb[l * 20 + cur] + bout[cur];
    }
  }
#pragma unroll
  for (int o = 32; o > 0; o >>= 1) {
    sc += __shfl_xor(sc, o, 64);
    cnt += __shfl_xor(cnt, o, 64);
  }
  if (tid == 0) {
    int t0 = tg[0];
    sc += start_t[t0] + ef[t0] + eb[t0] + bout[t0];
    sc += end_t[tg[cnt - 1]];
    partial[b] = sc - logZ;
  }
}

// ---------------------------------------------------------------------------
// K3: final reduction -> |sum|, f32 output.
// ---------------------------------------------------------------------------
__global__ __launch_bounds__(64) void final_kernel(const float* __restrict__ partial,
                                                   float* __restrict__ out) {
  int tid = threadIdx.x;
  float s = partial[tid] + partial[tid + 64];
#pragma unroll
  for (int o = 32; o > 0; o >>= 1) s += __shfl_xor(s, o, 64);
  if (tid == 0) out[0] = fabsf(s);
}

// ---------------------------------------------------------------------------
extern "C" void kernel_launch(void* const* d_in, const int* in_sizes, int n_in,
                              void* d_out, int out_size, void* d_ws, size_t ws_size,
                              hipStream_t stream) {
  const int* sent = (const int*)d_in[0];
  const int* tags = (const int*)d_in[1];
  const int* maski = (const int*)d_in[2];
  const float* emb = (const float*)d_in[3];
  const float* Wih_f = (const float*)d_in[4];
  const float* Whh_f = (const float*)d_in[5];
  const float* bih_f = (const float*)d_in[6];
  const float* bhh_f = (const float*)d_in[7];
  const float* Wih_b = (const float*)d_in[8];
  const float* Whh_b = (const float*)d_in[9];
  const float* bih_b = (const float*)d_in[10];
  const float* bhh_b = (const float*)d_in[11];
  const float* Wout = (const float*)d_in[12];
  const float* bout = (const float*)d_in[13];
  const float* trans = (const float*)d_in[14];
  const float* start_t = (const float*)d_in[15];
  const float* end_t = (const float*)d_in[16];

  char* ws = (char*)d_ws;
  float* em_base = (float*)ws;
  float* em_f = em_base;
  float* em_b = em_base + 128 * 512 * 20;
  long* whh_f8 = (long*)(ws + 10485760);
  long* wih_f8 = (long*)(ws + 11010048);
  long* wout_f8 = (long*)(ws + 11272192);
  float* bias_d = (float*)(ws + 11288576);
  float* partial = (float*)(ws + 11296768);

  prep_kernel<<<400, 256, 0, stream>>>(Whh_f, Whh_b, Wih_f, Wih_b, Wout,
                                       bih_f, bhh_f, bih_b, bhh_b,
                                       whh_f8, wih_f8, wout_f8, bias_d);
  lstm_kernel<<<16, 512, 0, stream>>>(sent, emb, whh_f8, wih_f8, wout_f8,
                                      bias_d, em_base);
  crf_kernel<<<128, 64, 0, stream>>>(em_f, em_b, tags, maski, bout, trans,
                                     start_t, end_t, partial);
  final_kernel<<<1, 64, 0, stream>>>(partial, (float*)d_out);
}

// Round 7
// 2297.962 us; speedup vs baseline: 1.1759x; 1.1759x over previous
//
#include <hip/hip_runtime.h>

// ---------------------------------------------------------------------------
// BiLSTM-CRF forward loss on MI355X (gfx950).
//
// Round-7: same structure as round 6 (one WG per (dir,batch-tile), fp8
// weights intended register-resident, LDS-closed recurrence), with the ONE
// fix the round-6 counters demanded: VGPR_Count was 128 < the 192 needed for
// wh+wx, i.e. the allocator (targeting default occupancy) refused the
// weight residency and re-streamed weights from L2 every step (4.85us/step).
//   1) __launch_bounds__(512, 2): 2 waves/EU = our own 8-wave block, 1
//      block/CU -> 256-VGPR budget per wave.
//   2) gate GEMM split into two straight-line halves (acc[4] live, not
//      acc[8]) to shape peak pressure; all reg-array indices compile-time.
// Contract notes (rounds 0-3): output f32; mask int32.
// Workspace layout (bytes):
//   [0)         em: [2][128][512][20] f32            (10485760)
//   [10485760)  whh_f8: [2][64nt][8kt][64lane] i64   (524288)
//   [11010048)  wih_f8: [2][64nt][4kt][64lane] i64   (262144)
//   [11272192)  wout_f8: [2][2nt][8kt][64lane] i64   (16384)
//   [11288576)  bias: [2][1024] f32                  (8192)
//   [11296768)  partial: [128] f32
// ---------------------------------------------------------------------------

typedef float f32x4 __attribute__((ext_vector_type(4)));

#define MFMAF8(a, b, c) \
  __builtin_amdgcn_mfma_f32_16x16x32_fp8_fp8((a), (b), (c), 0, 0, 0)

__device__ __forceinline__ unsigned short f2bf(float x) {
  unsigned u = __float_as_uint(x);
  u += 0x7FFFu + ((u >> 16) & 1u);  // RNE
  return (unsigned short)(u >> 16);
}
__device__ __forceinline__ float bf2f(unsigned short h) {
  return __uint_as_float(((unsigned)h) << 16);
}
__device__ __forceinline__ float sigm(float x) {
  return __builtin_amdgcn_rcpf(1.f + __expf(-x));
}
__device__ __forceinline__ float tanh_(float x) {
  float e = __expf(2.f * x);
  return (e - 1.f) * __builtin_amdgcn_rcpf(e + 1.f);
}
__device__ __forceinline__ unsigned pack_fp8x4(float a, float b, float c, float d) {
  int p = __builtin_amdgcn_cvt_pk_fp8_f32(a, b, 0, false);
  p = __builtin_amdgcn_cvt_pk_fp8_f32(c, d, p, true);
  return (unsigned)p;
}

// ---------------------------------------------------------------------------
// K0: weight prep: f32 -> fp8 e4m3 MFMA B-fragments.
// Frag (ntile n, kt): lane l, byte e <- W[n*16+(l&15)][kt*32+(l>>4)*8+e]
// ---------------------------------------------------------------------------
__global__ __launch_bounds__(256) void prep_kernel(
    const float* __restrict__ Whh_f, const float* __restrict__ Whh_b,
    const float* __restrict__ Wih_f, const float* __restrict__ Wih_b,
    const float* __restrict__ Wout,
    const float* __restrict__ bih_f, const float* __restrict__ bhh_f,
    const float* __restrict__ bih_b, const float* __restrict__ bhh_b,
    long* __restrict__ whh, long* __restrict__ wih, long* __restrict__ wout,
    float* __restrict__ bias) {
  int bid = blockIdx.x, tid = threadIdx.x;
  if (bid < 256) {  // Whh: gid in [0, 65536)
    int gid = bid * 256 + tid;
    int l = gid & 63, kt = (gid >> 6) & 7, n = (gid >> 9) & 63, dir = gid >> 15;
    const float* src = dir ? Whh_b : Whh_f;
    int row = n * 16 + (l & 15), k0 = kt * 32 + ((l >> 4) << 3);
    float v[8];
#pragma unroll
    for (int e = 0; e < 8; ++e) v[e] = src[row * 256 + k0 + e];
    unsigned lo = pack_fp8x4(v[0], v[1], v[2], v[3]);
    unsigned hi = pack_fp8x4(v[4], v[5], v[6], v[7]);
    whh[gid] = (long)lo | ((long)hi << 32);
  } else if (bid < 384) {  // Wih: gid in [0, 32768)
    int gid = (bid - 256) * 256 + tid;
    int l = gid & 63, kt = (gid >> 6) & 3, n = (gid >> 8) & 63, dir = gid >> 14;
    const float* src = dir ? Wih_b : Wih_f;
    int row = n * 16 + (l & 15), k0 = kt * 32 + ((l >> 4) << 3);
    float v[8];
#pragma unroll
    for (int e = 0; e < 8; ++e) {
      int k = k0 + e;
      v[e] = (k < 100) ? src[row * 100 + k] : 0.f;
    }
    unsigned lo = pack_fp8x4(v[0], v[1], v[2], v[3]);
    unsigned hi = pack_fp8x4(v[4], v[5], v[6], v[7]);
    wih[gid] = (long)lo | ((long)hi << 32);
  } else if (bid < 392) {  // Wout: gid in [0, 2048)
    int gid = (bid - 384) * 256 + tid;
    if (gid < 2048) {
      int l = gid & 63, kt = (gid >> 6) & 7, n = (gid >> 9) & 1, dir = gid >> 10;
      int colt = n * 16 + (l & 15), k0 = kt * 32 + ((l >> 4) << 3);
      float v[8];
#pragma unroll
      for (int e = 0; e < 8; ++e)
        v[e] = (colt < 20) ? Wout[colt * 512 + dir * 256 + k0 + e] : 0.f;
      unsigned lo = pack_fp8x4(v[0], v[1], v[2], v[3]);
      unsigned hi = pack_fp8x4(v[4], v[5], v[6], v[7]);
      wout[gid] = (long)lo | ((long)hi << 32);
    }
  } else {  // bias: idx in [0, 2048)
    int idx = (bid - 392) * 256 + tid;
    if (idx < 2048) {
      int dir = idx >> 10, c = idx & 1023;
      bias[idx] = dir ? (bih_b[c] + bhh_b[c]) : (bih_f[c] + bhh_f[c]);
    }
  }
}

// ---------------------------------------------------------------------------
// K1: BiLSTM recurrence, one WG per (dir, batch-tile). grid=16, block=512.
// Wave w owns gate cols [w*128, (w+1)*128) = 8 ntiles of 16.
// __launch_bounds__(512, 2): 1 block/CU, 256-VGPR budget -> weights resident.
// ---------------------------------------------------------------------------
__global__ __launch_bounds__(512, 2) void lstm_kernel(
    const int* __restrict__ sent, const float* __restrict__ emb,
    const long* __restrict__ whh, const long* __restrict__ wih,
    const long* __restrict__ wout, const float* __restrict__ bias,
    float* __restrict__ em_out)  // [2][128][512][20]
{
  __shared__ unsigned char h_lds[16][272];      // fp8 h(t-1), 256 data + pad
  __shared__ unsigned char x_lds[2][16][136];   // fp8 x, double-buffered
  __shared__ unsigned short g_T[1024][18];      // bf16 gates [col][row]
  __shared__ long wout_lds[2][8][64];           // fp8 Wout frags [nt][kt][lane]
  __shared__ float bias_lds[1024];

  const int tid = threadIdx.x;
  const int lid = tid & 63, w = tid >> 6;
  const int gid = blockIdx.x, dir = gid >> 3, bt = gid & 7, r0 = bt * 16;

  const int arow = lid & 15;       // A/C tile row-lane
  const int aq = lid >> 4;         // quarter
  const int rb = aq * 4;           // C-frag row base

  // ---- persistent fp8 weights in registers: 128+64 VGPRs ----
  long wh[8][8], wx[8][4];
  {
    const long* whh_d = whh + dir * 32768;
    const long* wih_d = wih + dir * 16384;
#pragma unroll
    for (int n = 0; n < 8; ++n) {
      int nt = w * 8 + n;
#pragma unroll
      for (int kt = 0; kt < 8; ++kt) wh[n][kt] = whh_d[(nt * 8 + kt) * 64 + lid];
#pragma unroll
      for (int kt = 0; kt < 4; ++kt) wx[n][kt] = wih_d[(nt * 4 + kt) * 64 + lid];
    }
  }
  // Wout + bias -> LDS
  {
    const long* wo_d = wout + dir * 1024;
    ((long*)wout_lds)[tid] = wo_d[tid];
    ((long*)wout_lds)[tid + 512] = wo_d[tid + 512];
    bias_lds[tid] = bias[dir * 1024 + tid];
    bias_lds[tid + 512] = bias[dir * 1024 + tid + 512];
  }
  // zero h, x (incl. padding)
  for (int i = tid; i < 16 * 272; i += 512) ((unsigned char*)h_lds)[i] = 0;
  for (int i = tid; i < 2 * 16 * 136; i += 512) ((unsigned char*)x_lds)[i] = 0;

  // h/c ownership: thread <-> (row ur, hidden cols ucg*8 .. +8)
  const int ur = tid & 15, ucg = tid >> 4;
  float creg[8];
#pragma unroll
  for (int j = 0; j < 8; ++j) creg[j] = 0.f;

  // x gather mapping: 400 chunks = (row 0..15) x (25 float4)
  const int rowA = tid / 25, cgA = tid - rowA * 25;
  const bool hasX = (tid < 400);

  // prologue: stage x(0)
  if (hasX) {
    int t0 = dir ? 511 : 0;
    int sid = sent[(r0 + rowA) * 512 + t0];
    float4 v = *(const float4*)&emb[sid * 100 + cgA * 4];
    *(unsigned*)&x_lds[0][rowA][cgA * 4] = pack_fp8x4(v.x, v.y, v.z, v.w);
  }
  __syncthreads();

  for (int t = 0; t < 512; ++t) {
    // issue x(t+1) gather early (latency hides under GEMM + update)
    float4 xN;
    const bool haveN = hasX && (t < 511);
    if (haveN) {
      int te = dir ? (511 - (t + 1)) : (t + 1);
      int sid = sent[(r0 + rowA) * 512 + te];
      xN = *(const float4*)&emb[sid * 100 + cgA * 4];
    }

    const unsigned char(*xb)[136] =
        (const unsigned char(*)[136])x_lds[t & 1];

    // ---- gate GEMM half A: ntiles 0..3 (48 fp8 MFMA) ----
    {
      f32x4 acc[4];
#pragma unroll
      for (int n = 0; n < 4; ++n) {
        float bb = bias_lds[w * 128 + n * 16 + arow];
        f32x4 a = {bb, bb, bb, bb};
        acc[n] = a;
      }
#pragma unroll
      for (int kt = 0; kt < 8; ++kt) {
        long a8 = *(const long*)&h_lds[arow][kt * 32 + aq * 8];
#pragma unroll
        for (int n = 0; n < 4; ++n) acc[n] = MFMAF8(a8, wh[n][kt], acc[n]);
      }
#pragma unroll
      for (int kt = 0; kt < 4; ++kt) {
        long a8 = *(const long*)&xb[arow][kt * 32 + aq * 8];
#pragma unroll
        for (int n = 0; n < 4; ++n) acc[n] = MFMAF8(a8, wx[n][kt], acc[n]);
      }
#pragma unroll
      for (int n = 0; n < 4; ++n) {
        int colL = w * 128 + n * 16 + arow;
        *(unsigned*)&g_T[colL][rb] =
            (unsigned)f2bf(acc[n][0]) | ((unsigned)f2bf(acc[n][1]) << 16);
        *(unsigned*)&g_T[colL][rb + 2] =
            (unsigned)f2bf(acc[n][2]) | ((unsigned)f2bf(acc[n][3]) << 16);
      }
    }
    // ---- gate GEMM half B: ntiles 4..7 ----
    {
      f32x4 acc[4];
#pragma unroll
      for (int n = 0; n < 4; ++n) {
        float bb = bias_lds[w * 128 + (n + 4) * 16 + arow];
        f32x4 a = {bb, bb, bb, bb};
        acc[n] = a;
      }
#pragma unroll
      for (int kt = 0; kt < 8; ++kt) {
        long a8 = *(const long*)&h_lds[arow][kt * 32 + aq * 8];
#pragma unroll
        for (int n = 0; n < 4; ++n) acc[n] = MFMAF8(a8, wh[n + 4][kt], acc[n]);
      }
#pragma unroll
      for (int kt = 0; kt < 4; ++kt) {
        long a8 = *(const long*)&xb[arow][kt * 32 + aq * 8];
#pragma unroll
        for (int n = 0; n < 4; ++n) acc[n] = MFMAF8(a8, wx[n + 4][kt], acc[n]);
      }
#pragma unroll
      for (int n = 0; n < 4; ++n) {
        int colL = w * 128 + (n + 4) * 16 + arow;
        *(unsigned*)&g_T[colL][rb] =
            (unsigned)f2bf(acc[n][0]) | ((unsigned)f2bf(acc[n][1]) << 16);
        *(unsigned*)&g_T[colL][rb + 2] =
            (unsigned)f2bf(acc[n][2]) | ((unsigned)f2bf(acc[n][3]) << 16);
      }
    }

    // ---- emissions for h(t-1): waves 0-1, h_lds still holds h(t-1) ----
    if (w < 2 && t > 0) {
      f32x4 e = {0.f, 0.f, 0.f, 0.f};
#pragma unroll
      for (int kt = 0; kt < 8; ++kt) {
        long a8 = *(const long*)&h_lds[arow][kt * 32 + aq * 8];
        e = MFMAF8(a8, wout_lds[w][kt][lid], e);
      }
      int col = w * 16 + arow;
      if (col < 20) {
        int tp = dir ? (512 - t) : (t - 1);
        int base = ((dir * 128 + r0 + rb) * 512 + tp) * 20 + col;
#pragma unroll
        for (int r = 0; r < 4; ++r) em_out[base + r * 10240] = e[r];
      }
    }
    __syncthreads();  // B2: gates ready; all h_lds/x reads done

    // ---- h/c update: 8 hidden cols per thread ----
    {
      float hv[8];
#pragma unroll
      for (int j = 0; j < 8; ++j) {
        int c = ucg * 8 + j;
        float xi = bf2f(g_T[c][ur]);
        float xf = bf2f(g_T[256 + c][ur]);
        float xg = bf2f(g_T[512 + c][ur]);
        float xo = bf2f(g_T[768 + c][ur]);
        float cc = sigm(xf) * creg[j] + sigm(xi) * tanh_(xg);
        creg[j] = cc;
        hv[j] = sigm(xo) * tanh_(cc);
      }
      unsigned lo = pack_fp8x4(hv[0], hv[1], hv[2], hv[3]);
      unsigned hi = pack_fp8x4(hv[4], hv[5], hv[6], hv[7]);
      *(long*)&h_lds[ur][ucg * 8] = (long)lo | ((long)hi << 32);
    }
    // ---- x(t+1) -> LDS (other buffer) ----
    if (haveN) {
      *(unsigned*)&x_lds[(t + 1) & 1][rowA][cgA * 4] =
          pack_fp8x4(xN.x, xN.y, xN.z, xN.w);
    }
    __syncthreads();  // B3: h(t) + x(t+1) staged
  }

  // final emissions for h(511)
  if (w < 2) {
    f32x4 e = {0.f, 0.f, 0.f, 0.f};
#pragma unroll
    for (int kt = 0; kt < 8; ++kt) {
      long a8 = *(const long*)&h_lds[arow][kt * 32 + aq * 8];
      e = MFMAF8(a8, wout_lds[w][kt][lid], e);
    }
    int col = w * 16 + arow;
    if (col < 20) {
      int tp = dir ? 0 : 511;
      int base = ((dir * 128 + r0 + rb) * 512 + tp) * 20 + col;
#pragma unroll
      for (int r = 0; r < 4; ++r) em_out[base + r * 10240] = e[r];
    }
  }
}

// ---------------------------------------------------------------------------
// K2: CRF gold score + forward algorithm. 128 blocks x 64 threads.
// ---------------------------------------------------------------------------
__global__ __launch_bounds__(64) void crf_kernel(
    const float* __restrict__ emf, const float* __restrict__ embk,
    const int* __restrict__ tags, const int* __restrict__ maski,
    const float* __restrict__ bout, const float* __restrict__ trans,
    const float* __restrict__ start_t, const float* __restrict__ end_t,
    float* __restrict__ partial) {
  __shared__ float tr[400];
  const int b = blockIdx.x, tid = threadIdx.x;
  for (int i = tid; i < 400; i += 64) tr[i] = trans[i];
  __syncthreads();

  const int tp = tid;
  const bool act = tp < 20;
  float eT[20];
  if (act) {
#pragma unroll
    for (int t2 = 0; t2 < 20; ++t2) eT[t2] = __expf(tr[t2 * 20 + tp]);
  }
  const float* ef = emf + (size_t)b * 10240;
  const float* eb = embk + (size_t)b * 10240;
  const float bo = act ? bout[tp] : 0.f;

  float a = act ? (start_t[tp] + ef[tp] + eb[tp] + bo) : -1e30f;

  float efn = 0.f, ebn = 0.f;
  if (act) { efn = ef[20 + tp]; ebn = eb[20 + tp]; }

  for (int l = 1; l < 512; ++l) {
    float e_cur = efn + ebn + bo;
    if (act && l + 1 < 512) { efn = ef[(l + 1) * 20 + tp]; ebn = eb[(l + 1) * 20 + tp]; }
    float m = a;
#pragma unroll
    for (int o = 16; o > 0; o >>= 1) m = fmaxf(m, __shfl_xor(m, o, 32));
    float p = __expf(a - m);
    float s = 0.f;
#pragma unroll
    for (int t2 = 0; t2 < 20; ++t2) s += __shfl(p, t2, 32) * eT[t2];
    float anew = m + __logf(s) + e_cur;
    int mk = maski[b * 512 + l];
    if (act && mk) a = anew;
  }
  float v = act ? (a + end_t[tp]) : -1e30f;
  float m2 = v;
#pragma unroll
  for (int o = 16; o > 0; o >>= 1) m2 = fmaxf(m2, __shfl_xor(m2, o, 32));
  float s2 = __expf(v - m2);
#pragma unroll
  for (int o = 16; o > 0; o >>= 1) s2 += __shfl_xor(s2, o, 32);
  float logZ = m2 + __logf(s2);

  const int* tg = tags + b * 512;
  float sc = 0.f;
  int cnt = 0;
  for (int l = tid; l < 512; l += 64) {
    int mk = maski[b * 512 + l];
    cnt += mk ? 1 : 0;
    if (l >= 1 && mk) {
      int cur = tg[l], prev = tg[l - 1];
      sc += tr[prev * 20 + cur] + ef[l * 20 + cur] + eb[l * 20 + cur] + bout[cur];
    }
  }
#pragma unroll
  for (int o = 32; o > 0; o >>= 1) {
    sc += __shfl_xor(sc, o, 64);
    cnt += __shfl_xor(cnt, o, 64);
  }
  if (tid == 0) {
    int t0 = tg[0];
    sc += start_t[t0] + ef[t0] + eb[t0] + bout[t0];
    sc += end_t[tg[cnt - 1]];
    partial[b] = sc - logZ;
  }
}

// ---------------------------------------------------------------------------
// K3: final reduction -> |sum|, f32 output.
// ---------------------------------------------------------------------------
__global__ __launch_bounds__(64) void final_kernel(const float* __restrict__ partial,
                                                   float* __restrict__ out) {
  int tid = threadIdx.x;
  float s = partial[tid] + partial[tid + 64];
#pragma unroll
  for (int o = 32; o > 0; o >>= 1) s += __shfl_xor(s, o, 64);
  if (tid == 0) out[0] = fabsf(s);
}

// ---------------------------------------------------------------------------
extern "C" void kernel_launch(void* const* d_in, const int* in_sizes, int n_in,
                              void* d_out, int out_size, void* d_ws, size_t ws_size,
                              hipStream_t stream) {
  const int* sent = (const int*)d_in[0];
  const int* tags = (const int*)d_in[1];
  const int* maski = (const int*)d_in[2];
  const float* emb = (const float*)d_in[3];
  const float* Wih_f = (const float*)d_in[4];
  const float* Whh_f = (const float*)d_in[5];
  const float* bih_f = (const float*)d_in[6];
  const float* bhh_f = (const float*)d_in[7];
  const float* Wih_b = (const float*)d_in[8];
  const float* Whh_b = (const float*)d_in[9];
  const float* bih_b = (const float*)d_in[10];
  const float* bhh_b = (const float*)d_in[11];
  const float* Wout = (const float*)d_in[12];
  const float* bout = (const float*)d_in[13];
  const float* trans = (const float*)d_in[14];
  const float* start_t = (const float*)d_in[15];
  const float* end_t = (const float*)d_in[16];

  char* ws = (char*)d_ws;
  float* em_base = (float*)ws;
  float* em_f = em_base;
  float* em_b = em_base + 128 * 512 * 20;
  long* whh_f8 = (long*)(ws + 10485760);
  long* wih_f8 = (long*)(ws + 11010048);
  long* wout_f8 = (long*)(ws + 11272192);
  float* bias_d = (float*)(ws + 11288576);
  float* partial = (float*)(ws + 11296768);

  prep_kernel<<<400, 256, 0, stream>>>(Whh_f, Whh_b, Wih_f, Wih_b, Wout,
                                       bih_f, bhh_f, bih_b, bhh_b,
                                       whh_f8, wih_f8, wout_f8, bias_d);
  lstm_kernel<<<16, 512, 0, stream>>>(sent, emb, whh_f8, wih_f8, wout_f8,
                                      bias_d, em_base);
  crf_kernel<<<128, 64, 0, stream>>>(em_f, em_b, tags, maski, bout, trans,
                                     start_t, end_t, partial);
  final_kernel<<<1, 64, 0, stream>>>(partial, (float*)d_out);
}